// Round 1
// baseline (81598.291 us; speedup 1.0000x reference)
//
#include <hip/hip_runtime.h>

#define HH    51
#define G4    204        // 4*H
#define T_SEQ 1024
#define T_TOT 1088       // T + future(64)
#define B_TOT 4096
#define MT    16         // batch rows per block
#define NTH   512        // 8 waves
#define WTR   208        // transposed-weight row stride (dwords), lane-consecutive j
#define HS    52         // h row stride (52*4B = 208B, 16B-aligned rows)

// ---- LDS offsets (in floats) ----
#define OFF_WT1 0
#define SZ_WT   (52*WTR)             // 10816
#define OFF_WT2 (OFF_WT1 + SZ_WT)    // W_ih2
#define OFF_WT3 (OFF_WT2 + SZ_WT)    // W_hh2
#define OFF_G   (OFF_WT3 + SZ_WT)    // gates [16][204]
#define OFF_H1  (OFF_G + MT*G4)
#define OFF_H2  (OFF_H1 + MT*HS)
#define OFF_XB  (OFF_H2 + MT*HS)     // x double buffer [2][16][16]
#define OFF_CB1 (OFF_XB + 2*MT*16)
#define OFF_CB2 (OFF_CB1 + 208)
#define OFF_WI1 (OFF_CB2 + 208)
#define OFF_WL  (OFF_WI1 + 208)
#define OFF_XC  (OFF_WL + 64)        // current x per batch row [16]
#define OFF_BL  (OFF_XC + 16)
#define TOT_F   (OFF_BL + 8)         // 38600 floats = 154,400 B

__device__ __forceinline__ float sigm(float v) { return 1.f / (1.f + __expf(-v)); }
__device__ __forceinline__ float tanh_f(float v) { return 1.f - 2.f / (1.f + __expf(2.f * v)); }

__launch_bounds__(NTH, 2)
__global__ void lstm_seq_kernel(const float* __restrict__ x,
                                const float* __restrict__ Wih1,
                                const float* __restrict__ Whh1,
                                const float* __restrict__ bih1,
                                const float* __restrict__ bhh1,
                                const float* __restrict__ Wih2,
                                const float* __restrict__ Whh2,
                                const float* __restrict__ bih2,
                                const float* __restrict__ bhh2,
                                const float* __restrict__ Wlin,
                                const float* __restrict__ blin,
                                float* __restrict__ out)
{
  extern __shared__ float sm[];
  const int tid = threadIdx.x;
  const int bg0 = blockIdx.x * MT;

  // zero all LDS (also zero-inits h1/h2 state and all pad columns)
  for (int i = tid; i < TOT_F; i += NTH) sm[i] = 0.f;
  __syncthreads();

  // stage weights transposed: WT[k][j] = W[j][k]; row k=51 stays zero (K-pad)
  for (int i = tid; i < G4 * HH; i += NTH) {
    const int j = i / HH, k = i - j * HH;
    sm[OFF_WT1 + k * WTR + j] = Whh1[i];
    sm[OFF_WT2 + k * WTR + j] = Wih2[i];
    sm[OFF_WT3 + k * WTR + j] = Whh2[i];
  }
  for (int jj = tid; jj < G4; jj += NTH) {
    sm[OFF_CB1 + jj] = bih1[jj] + bhh1[jj];
    sm[OFF_CB2 + jj] = bih2[jj] + bhh2[jj];
    sm[OFF_WI1 + jj] = Wih1[jj];
  }
  if (tid < HH) sm[OFF_WL + tid] = Wlin[tid];
  if (tid == 0) sm[OFF_BL] = blin[0];
  // first x chunk (steps 0..15)
  if (tid < 256) {
    const int b = tid >> 4, tt = tid & 15;
    sm[OFF_XB + b * 16 + tt] = x[(size_t)(bg0 + b) * T_SEQ + tt];
  }
  __syncthreads();
  if (tid < MT) sm[OFF_XC + tid] = sm[OFF_XB + tid * 16];
  __syncthreads();

  // gates-phase mapping: thread -> (gate j, batch half)
  const int j   = tid & 255;
  const bool ja = (j < G4);
  const int bb  = (tid >> 8) * 8;     // batch base: 0 or 8
  // act-phase mapping: wave wv handles batch rows wv and wv+8, lane = hidden k
  const int lane = tid & 63;
  const int wv   = tid >> 6;

  float c1[2] = {0.f, 0.f};
  float c2[2] = {0.f, 0.f};

  for (int t = 0; t < T_TOT; ++t) {
    // prefetch next 16-step x chunk into the other buffer half
    if ((t & 15) == 0) {
      const int nt = t + 16;
      if (nt < T_SEQ && tid < 256) {
        const int b = tid >> 4, tt = tid & 15;
        sm[OFF_XB + (((nt >> 4) & 1) ? 256 : 0) + b * 16 + tt] =
            x[(size_t)(bg0 + b) * T_SEQ + nt + tt];
      }
    }
    // ---- phase A: gates1 = cb1 + Wih1*x + Whh1 @ h1_old ----
    if (ja) {
      float acc[8];
      const float cb = sm[OFF_CB1 + j];
      const float wi = sm[OFF_WI1 + j];
      #pragma unroll
      for (int r = 0; r < 8; ++r) acc[r] = cb + wi * sm[OFF_XC + bb + r];
      #pragma unroll
      for (int c = 0; c < 13; ++c) {
        const float w0 = sm[OFF_WT1 + (4 * c + 0) * WTR + j];
        const float w1 = sm[OFF_WT1 + (4 * c + 1) * WTR + j];
        const float w2 = sm[OFF_WT1 + (4 * c + 2) * WTR + j];
        const float w3 = sm[OFF_WT1 + (4 * c + 3) * WTR + j];
        #pragma unroll
        for (int r = 0; r < 8; ++r) {
          const float4 hv = *reinterpret_cast<const float4*>(&sm[OFF_H1 + (bb + r) * HS + 4 * c]);
          acc[r] += w0 * hv.x + w1 * hv.y + w2 * hv.z + w3 * hv.w;
        }
      }
      #pragma unroll
      for (int r = 0; r < 8; ++r) sm[OFF_G + (bb + r) * G4 + j] = acc[r];
    }
    __syncthreads();
    // ---- phase B: act1 -> h1_new, c1 ----
    #pragma unroll
    for (int p = 0; p < 2; ++p) {
      const int b = wv + 8 * p;
      if (lane < HH) {
        const float gi = sm[OFF_G + b * G4 + lane];
        const float gf = sm[OFF_G + b * G4 + 51 + lane];
        const float gg = sm[OFF_G + b * G4 + 102 + lane];
        const float go = sm[OFF_G + b * G4 + 153 + lane];
        const float cn = sigm(gf) * c1[p] + sigm(gi) * tanh_f(gg);
        c1[p] = cn;
        sm[OFF_H1 + b * HS + lane] = sigm(go) * tanh_f(cn);
      }
    }
    __syncthreads();
    // ---- phase C: gates2 = cb2 + Wih2 @ h1_new + Whh2 @ h2_old ----
    if (ja) {
      float acc[8];
      const float cb = sm[OFF_CB2 + j];
      #pragma unroll
      for (int r = 0; r < 8; ++r) acc[r] = cb;
      #pragma unroll
      for (int c = 0; c < 13; ++c) {
        const float w0 = sm[OFF_WT2 + (4 * c + 0) * WTR + j];
        const float w1 = sm[OFF_WT2 + (4 * c + 1) * WTR + j];
        const float w2 = sm[OFF_WT2 + (4 * c + 2) * WTR + j];
        const float w3 = sm[OFF_WT2 + (4 * c + 3) * WTR + j];
        #pragma unroll
        for (int r = 0; r < 8; ++r) {
          const float4 hv = *reinterpret_cast<const float4*>(&sm[OFF_H1 + (bb + r) * HS + 4 * c]);
          acc[r] += w0 * hv.x + w1 * hv.y + w2 * hv.z + w3 * hv.w;
        }
      }
      #pragma unroll
      for (int c = 0; c < 13; ++c) {
        const float w0 = sm[OFF_WT3 + (4 * c + 0) * WTR + j];
        const float w1 = sm[OFF_WT3 + (4 * c + 1) * WTR + j];
        const float w2 = sm[OFF_WT3 + (4 * c + 2) * WTR + j];
        const float w3 = sm[OFF_WT3 + (4 * c + 3) * WTR + j];
        #pragma unroll
        for (int r = 0; r < 8; ++r) {
          const float4 hv = *reinterpret_cast<const float4*>(&sm[OFF_H2 + (bb + r) * HS + 4 * c]);
          acc[r] += w0 * hv.x + w1 * hv.y + w2 * hv.z + w3 * hv.w;
        }
      }
      #pragma unroll
      for (int r = 0; r < 8; ++r) sm[OFF_G + (bb + r) * G4 + j] = acc[r];
    }
    __syncthreads();
    // ---- phase D: act2 -> h2_new, c2; out = Wlin . h2 + blin; feed xcur ----
    #pragma unroll
    for (int p = 0; p < 2; ++p) {
      const int b = wv + 8 * p;
      float po = 0.f;
      if (lane < HH) {
        const float gi = sm[OFF_G + b * G4 + lane];
        const float gf = sm[OFF_G + b * G4 + 51 + lane];
        const float gg = sm[OFF_G + b * G4 + 102 + lane];
        const float go = sm[OFF_G + b * G4 + 153 + lane];
        const float cn = sigm(gf) * c2[p] + sigm(gi) * tanh_f(gg);
        c2[p] = cn;
        const float hn = sigm(go) * tanh_f(cn);
        sm[OFF_H2 + b * HS + lane] = hn;
        po = sm[OFF_WL + lane] * hn;
      }
      #pragma unroll
      for (int m = 32; m >= 1; m >>= 1) po += __shfl_xor(po, m, 64);
      if (lane == 0) {
        const float ov = po + sm[OFF_BL];
        out[(size_t)(bg0 + b) * T_TOT + t] = ov;
        const int t1 = t + 1;
        float nx;
        if (t1 < T_SEQ) nx = sm[OFF_XB + (((t1 >> 4) & 1) ? 256 : 0) + b * 16 + (t1 & 15)];
        else            nx = ov;   // autoregressive future phase
        sm[OFF_XC + b] = nx;
      }
    }
    __syncthreads();
  }
}

extern "C" void kernel_launch(void* const* d_in, const int* in_sizes, int n_in,
                              void* d_out, int out_size, void* d_ws, size_t ws_size,
                              hipStream_t stream) {
  const float* x    = (const float*)d_in[0];
  const float* Wih1 = (const float*)d_in[1];
  const float* Whh1 = (const float*)d_in[2];
  const float* bih1 = (const float*)d_in[3];
  const float* bhh1 = (const float*)d_in[4];
  const float* Wih2 = (const float*)d_in[5];
  const float* Whh2 = (const float*)d_in[6];
  const float* bih2 = (const float*)d_in[7];
  const float* bhh2 = (const float*)d_in[8];
  const float* Wlin = (const float*)d_in[9];
  const float* blin = (const float*)d_in[10];
  float* out = (float*)d_out;

  const size_t smem = (size_t)TOT_F * sizeof(float);  // ~150.8 KiB, fits 160 KiB LDS
  (void)hipFuncSetAttribute((const void*)lstm_seq_kernel,
                            hipFuncAttributeMaxDynamicSharedMemorySize, (int)smem);

  lstm_seq_kernel<<<B_TOT / MT, NTH, smem, stream>>>(
      x, Wih1, Whh1, bih1, bhh1, Wih2, Whh2, bih2, bhh2, Wlin, blin, out);
}